// Round 10
// baseline (391.230 us; speedup 1.0000x reference)
//
#include <hip/hip_runtime.h>

// FEM stiffness matvec KU = sum_e scatter(K_type(e) @ gather(U, e)).
//
// Round 10 = R9 + bf16 FILTERS in LDS (74.8 KB, stride 584 ushorts):
//  - LDS/block drops 148->79 KB => 2 blocks/CU (32 waves): doubles the
//    outstanding-gather pool. R9 post-mortem: K1 is latency-bound on the
//    U-gather at 16 waves/CU (~45 us exposure), not byte-bound (bf16-U and
//    12 B records moved nothing).
//  - filter reads halve: 72 ds_read_b128/elem (8 bf16 each) vs 144.
//  - stride 584 ushorts = 1168 B: 16 B-aligned, bank phase 4t%32 (8 phases)
//    => ~8 words/bank, near the conflict-free b128 floor.
// Numerics: bf16 K (+ bf16 U from R9) => KU err max ~0.5 << 1.43 threshold.
// Rest per R9: 2048-node buckets, 12 B records (11-bit local id in low
// mantissa bits), block-aggregated tail reservation, K2 LDS accumulate.

#define NTYPES    64
#define KSTRIDE_H 584            // ushorts per type: 1168 B, 16 B-aligned
#define RSHIFT    11
#define RNODES    2048
#define MAXB      512
#define CAP       10240          // mean 8180/bucket, huge slack
#define K1_TPB    1024
#define K2_TPB    512
#define PREP_TPB  256

typedef int          nint4  __attribute__((ext_vector_type(4)));
typedef unsigned int nuint2 __attribute__((ext_vector_type(2)));
typedef unsigned int nuint4 __attribute__((ext_vector_type(4)));

__device__ __forceinline__ unsigned bf16_rne(float f) {
    unsigned b = __float_as_uint(f);
    return (b + 0x7FFFu + ((b >> 16) & 1u)) >> 16;
}

// ---- phase 0: pack U -> bf16 triples in 8 B slots -------------------------

__global__ __launch_bounds__(PREP_TPB) void pack_u_kernel(
    const float* __restrict__ U, nuint2* __restrict__ Ub, int n_nodes)
{
    int n = blockIdx.x * PREP_TPB + threadIdx.x;
    if (n >= n_nodes) return;
    const float* up = U + (size_t)n * 3;
    unsigned bx = bf16_rne(up[0]);
    unsigned by = bf16_rne(up[1]);
    unsigned bz = bf16_rne(up[2]);
    nuint2 v = { bx | (by << 16), bz };
    Ub[n] = v;
}

// ---- phase 1: compute + bin ----------------------------------------------

__global__ __launch_bounds__(K1_TPB, 8) void feconv_bin_kernel(
    const nuint2* __restrict__ Ub,      // [N] packed bf16 x,y,z
    const float* __restrict__ K,        // [64, 24, 24]
    const int*   __restrict__ types,    // [E]
    const int*   __restrict__ nodIdx,   // [E, 8]
    float*       __restrict__ KU,       // overflow fallback only
    unsigned*    __restrict__ tails,    // [n_buckets]
    unsigned*    __restrict__ recs,     // [n_buckets * CAP * 3] words
    int n_elems, int n_buckets)
{
    extern __shared__ unsigned short sKb[];   // [64 * KSTRIDE_H] bf16
    __shared__ unsigned sCnt[MAXB];
    __shared__ unsigned sBase[MAXB];

    // stage filters as bf16
    for (int w = threadIdx.x; w < NTYPES * 576; w += K1_TPB) {
        int t = w / 576;
        int r = w - t * 576;
        sKb[t * KSTRIDE_H + r] = (unsigned short)bf16_rne(K[w]);
    }
    for (int i = threadIdx.x; i < n_buckets; i += K1_TPB) sCnt[i] = 0;
    __syncthreads();

    const int e = blockIdx.x * K1_TPB + threadIdx.x;
    int nodes[8];
    int tt = -1;

    // pass A: load connectivity (NT: stream-once), count bucket usage
    if (e < n_elems) {
        tt = __builtin_nontemporal_load(&types[e]);
        const nint4* q = (const nint4*)(nodIdx + (size_t)e * 8);
        nint4 a = __builtin_nontemporal_load(q);
        nint4 b = __builtin_nontemporal_load(q + 1);
        nodes[0] = a.x; nodes[1] = a.y; nodes[2] = a.z; nodes[3] = a.w;
        nodes[4] = b.x; nodes[5] = b.y; nodes[6] = b.z; nodes[7] = b.w;
#pragma unroll
        for (int j = 0; j < 8; ++j)
            atomicAdd(&sCnt[(unsigned)nodes[j] >> RSHIFT], 1u);
    }
    __syncthreads();

    // pass B: one global tail reservation per (block, bucket)
    for (int b = threadIdx.x; b < n_buckets; b += K1_TPB) {
        unsigned c = sCnt[b];
        sBase[b] = c ? atomicAdd(&tails[b], c) : 0u;
        sCnt[b] = 0;                     // reuse as local cursor
    }
    __syncthreads();

    // pass C: gather bf16 u_e, matvec (bf16 LDS b128 reads), 12 B records
    if (tt >= 0) {
        float ue[24];
#pragma unroll
        for (int j = 0; j < 8; ++j) {
            nuint2 v = Ub[nodes[j]];
            ue[3 * j + 0] = __uint_as_float(v.x << 16);
            ue[3 * j + 1] = __uint_as_float(v.x & 0xFFFF0000u);
            ue[3 * j + 2] = __uint_as_float(v.y << 16);
        }

        // type block base: KSTRIDE_H*2 B = 1168 B, 16 B-aligned
        const nuint4* Kt4 = (const nuint4*)(sKb + tt * KSTRIDE_H);
#pragma unroll
        for (int j = 0; j < 8; ++j) {
            float acc[3];
#pragma unroll
            for (int rr = 0; rr < 3; ++rr) {
                int i = 3 * j + rr;           // row index; 24 bf16 = 3 nuint4
                float a = 0.f;
#pragma unroll
                for (int q = 0; q < 3; ++q) {
                    nuint4 w = Kt4[i * 3 + q];
                    const float* u = ue + q * 8;
                    a += __uint_as_float(w.x << 16)         * u[0];
                    a += __uint_as_float(w.x & 0xFFFF0000u) * u[1];
                    a += __uint_as_float(w.y << 16)         * u[2];
                    a += __uint_as_float(w.y & 0xFFFF0000u) * u[3];
                    a += __uint_as_float(w.z << 16)         * u[4];
                    a += __uint_as_float(w.z & 0xFFFF0000u) * u[5];
                    a += __uint_as_float(w.w << 16)         * u[6];
                    a += __uint_as_float(w.w & 0xFFFF0000u) * u[7];
                }
                acc[rr] = a;
            }
            unsigned n = (unsigned)nodes[j];
            unsigned b = n >> RSHIFT;
            unsigned pos = sBase[b] + atomicAdd(&sCnt[b], 1u);
            if (pos < CAP) {
                // 12 B record: local id (11b) in low 4 mantissa bits of each
                unsigned local = n & (RNODES - 1);
                size_t base = 3 * ((size_t)b * CAP + pos);
                recs[base + 0] = (__float_as_uint(acc[0]) & ~15u) | (local & 15u);
                recs[base + 1] = (__float_as_uint(acc[1]) & ~15u) | ((local >> 4) & 15u);
                recs[base + 2] = (__float_as_uint(acc[2]) & ~15u) | (local >> 8);
            } else {  // statistically unreachable; absolute correctness
                atomicAdd(&KU[(size_t)n * 3 + 0], acc[0]);
                atomicAdd(&KU[(size_t)n * 3 + 1], acc[1]);
                atomicAdd(&KU[(size_t)n * 3 + 2], acc[2]);
            }
        }
    }
}

// ---- phase 2: accumulate per bucket --------------------------------------

__global__ __launch_bounds__(K2_TPB) void feconv_acc_kernel(
    const unsigned* __restrict__ recs,
    const unsigned* __restrict__ tails,
    float*          __restrict__ KU,     // [N, 3], pre-zeroed
    int n_nodes)
{
    __shared__ float sAcc[RNODES * 3];   // 24 KB
    const int b = blockIdx.x;

    for (int i = threadIdx.x; i < RNODES * 3; i += K2_TPB) sAcc[i] = 0.f;
    __syncthreads();

    unsigned cnt = tails[b];
    if (cnt > CAP) cnt = CAP;
    const unsigned* base = recs + 3 * ((size_t)b * CAP);
    for (unsigned i = threadIdx.x; i < cnt; i += K2_TPB) {
        unsigned w0 = base[3 * i + 0];
        unsigned w1 = base[3 * i + 1];
        unsigned w2 = base[3 * i + 2];
        unsigned local = (w0 & 15u) | ((w1 & 15u) << 4) | ((w2 & 7u) << 8);
        unsigned o = local * 3;
        atomicAdd(&sAcc[o + 0], __uint_as_float(w0 & ~15u));  // ds_add_f32
        atomicAdd(&sAcc[o + 1], __uint_as_float(w1 & ~15u));
        atomicAdd(&sAcc[o + 2], __uint_as_float(w2 & ~15u));
    }
    __syncthreads();

    const int nbase = b * RNODES;
    int limit = n_nodes - nbase;
    if (limit > RNODES) limit = RNODES;
    limit *= 3;
    float* out = KU + (size_t)nbase * 3;
    for (int i = threadIdx.x; i < limit; i += K2_TPB) out[i] += sAcc[i];
}

// ---- fallback (round-0 style) --------------------------------------------

__global__ __launch_bounds__(256) void feconv_elem_kernel(
    const float* __restrict__ U, const float* __restrict__ K,
    const int* __restrict__ types, const int* __restrict__ nodIdx,
    float* __restrict__ KU, int n_elems)
{
    int e = blockIdx.x * blockDim.x + threadIdx.x;
    if (e >= n_elems) return;
    int t = types[e];
    const int4* idx4 = (const int4*)(nodIdx + (size_t)e * 8);
    int4 iA = idx4[0], iB = idx4[1];
    int nodes[8] = {iA.x, iA.y, iA.z, iA.w, iB.x, iB.y, iB.z, iB.w};
    float ue[24];
#pragma unroll
    for (int j = 0; j < 8; ++j) {
        const float* up = U + (size_t)nodes[j] * 3;
        ue[3 * j + 0] = up[0]; ue[3 * j + 1] = up[1]; ue[3 * j + 2] = up[2];
    }
    const float* Kt = K + (size_t)t * 576;
#pragma unroll
    for (int i = 0; i < 24; ++i) {
        const float4* row = (const float4*)(Kt + i * 24);
        float acc = 0.f;
#pragma unroll
        for (int q = 0; q < 6; ++q) {
            float4 k = row[q];
            acc += k.x * ue[4 * q + 0] + k.y * ue[4 * q + 1]
                 + k.z * ue[4 * q + 2] + k.w * ue[4 * q + 3];
        }
        atomicAdd(&KU[(size_t)nodes[i / 3] * 3 + (i % 3)], acc);
    }
}

extern "C" void kernel_launch(void* const* d_in, const int* in_sizes, int n_in,
                              void* d_out, int out_size, void* d_ws, size_t ws_size,
                              hipStream_t stream) {
    const float* U      = (const float*)d_in[0];
    const float* Kf     = (const float*)d_in[1];
    const int*   types  = (const int*)d_in[2];
    const int*   nodIdx = (const int*)d_in[3];
    float*       KU     = (float*)d_out;

    const int n_elems = in_sizes[2];
    const int n_nodes = in_sizes[0] / 3;
    const int n_buckets = (n_nodes + RNODES - 1) / RNODES;   // 489 for N=1M

    (void)hipMemsetAsync(KU, 0, (size_t)out_size * sizeof(float), stream);

    // ws layout: [0, 4096) tails | [4096, +8B*n_nodes) Ub | then recs words
    const size_t ub_off  = 4096;
    const size_t rec_off = ub_off + (((size_t)n_nodes * 8 + 255) & ~255ull);
    const size_t need    = rec_off + (size_t)n_buckets * CAP * 12;

    if (n_buckets <= MAXB && ws_size >= need) {
        unsigned* tails = (unsigned*)d_ws;
        nuint2*   Ub    = (nuint2*)((char*)d_ws + ub_off);
        unsigned* recs  = (unsigned*)((char*)d_ws + rec_off);

        (void)hipMemsetAsync(tails, 0, 4096, stream);

        int gridP = (n_nodes + PREP_TPB - 1) / PREP_TPB;
        pack_u_kernel<<<gridP, PREP_TPB, 0, stream>>>(U, Ub, n_nodes);

        size_t lds_bytes = (size_t)NTYPES * KSTRIDE_H * 2;   // 74,752 B
        int grid1 = (n_elems + K1_TPB - 1) / K1_TPB;
        feconv_bin_kernel<<<grid1, K1_TPB, lds_bytes, stream>>>(
            Ub, Kf, types, nodIdx, KU, tails, recs, n_elems, n_buckets);
        feconv_acc_kernel<<<n_buckets, K2_TPB, 0, stream>>>(
            recs, tails, KU, n_nodes);
    } else {
        int block = 256;
        int grid = (n_elems + block - 1) / block;
        feconv_elem_kernel<<<grid, block, 0, stream>>>(
            U, Kf, types, nodIdx, KU, n_elems);
    }
}

// Round 11
// 216.440 us; speedup vs baseline: 1.8076x; 1.8076x over previous
//
#include <hip/hip_runtime.h>

// FEM stiffness matvec KU = sum_e scatter(K_type(e) @ gather(U, e)).
//
// Round 11 = R9 (best verified: K1 99.5 us) + more memory-level parallelism:
//  - EPT=2: each thread owns 2 elements; ALL 16 Ub gather loads are issued
//    in pass A (immediately after connectivity), so HBM/L3 latency overlaps
//    pass A/B work + barrier; pass C consumes from registers.
//  - __launch_bounds__(1024, 4): VGPR cap 128. R10 lesson: (1024,8) forced
//    VGPR=32 -> scratch spills (FETCH 209->458 MB, WRITE 104->338 MB,
//    K1 100->250 us). Occupancy stays 16 waves/CU (LDS-limited, 148 KB).
// Carries from R8/R9: fp32 LDS filters stride 580 read as ds_read_b128,
// bf16-packed U (8 B/node), 12 B records (11-bit local id in low mantissa
// bits), 2048-node buckets, block-aggregated tail reservation, K2 LDS
// accumulate via ds_add_f32.

#define NTYPES    64
#define KSTRIDE   580            // fp32 words per type: 2320 B, 16 B-aligned
#define RSHIFT    11
#define RNODES    2048
#define MAXB      512
#define CAP       10240          // mean 8180/bucket, huge slack
#define K1_TPB    1024
#define K1_EPT    2
#define K1_CHUNK  (K1_TPB * K1_EPT)
#define K2_TPB    512
#define PREP_TPB  256

typedef int          nint4  __attribute__((ext_vector_type(4)));
typedef unsigned int nuint2 __attribute__((ext_vector_type(2)));

__device__ __forceinline__ unsigned bf16_rne(float f) {
    unsigned b = __float_as_uint(f);
    return (b + 0x7FFFu + ((b >> 16) & 1u)) >> 16;
}

// ---- phase 0: pack U -> bf16 triples in 8 B slots -------------------------

__global__ __launch_bounds__(PREP_TPB) void pack_u_kernel(
    const float* __restrict__ U, nuint2* __restrict__ Ub, int n_nodes)
{
    int n = blockIdx.x * PREP_TPB + threadIdx.x;
    if (n >= n_nodes) return;
    const float* up = U + (size_t)n * 3;
    unsigned bx = bf16_rne(up[0]);
    unsigned by = bf16_rne(up[1]);
    unsigned bz = bf16_rne(up[2]);
    nuint2 v = { bx | (by << 16), bz };
    Ub[n] = v;
}

// ---- phase 1: compute + bin ----------------------------------------------

__global__ __launch_bounds__(K1_TPB, 4) void feconv_bin_kernel(
    const nuint2* __restrict__ Ub,      // [N] packed bf16 x,y,z
    const float* __restrict__ K,        // [64, 24, 24]
    const int*   __restrict__ types,    // [E]
    const int*   __restrict__ nodIdx,   // [E, 8]
    float*       __restrict__ KU,       // overflow fallback only
    unsigned*    __restrict__ tails,    // [n_buckets]
    unsigned*    __restrict__ recs,     // [n_buckets * CAP * 3] words
    int n_elems, int n_buckets)
{
    extern __shared__ float sK[];       // [64 * KSTRIDE] words, per-type rows
    __shared__ unsigned sCnt[MAXB];
    __shared__ unsigned sBase[MAXB];

    for (int w = threadIdx.x; w < NTYPES * 576; w += K1_TPB) {
        int t = w / 576;
        int r = w - t * 576;
        sK[t * KSTRIDE + r] = K[w];
    }
    for (int i = threadIdx.x; i < n_buckets; i += K1_TPB) sCnt[i] = 0;
    __syncthreads();

    const int e0 = blockIdx.x * K1_CHUNK + threadIdx.x;
    int     nodes[K1_EPT][8];
    int     tt[K1_EPT];
    nuint2  uu[K1_EPT][8];              // in-flight packed gathers

    // pass A: connectivity + EARLY gather issue + bucket counting
#pragma unroll
    for (int k = 0; k < K1_EPT; ++k) {
        int e = e0 + k * K1_TPB;
        tt[k] = -1;
        if (e < n_elems) {
            tt[k] = __builtin_nontemporal_load(&types[e]);
            const nint4* q = (const nint4*)(nodIdx + (size_t)e * 8);
            nint4 a = __builtin_nontemporal_load(q);
            nint4 b = __builtin_nontemporal_load(q + 1);
            nodes[k][0] = a.x; nodes[k][1] = a.y; nodes[k][2] = a.z; nodes[k][3] = a.w;
            nodes[k][4] = b.x; nodes[k][5] = b.y; nodes[k][6] = b.z; nodes[k][7] = b.w;
#pragma unroll
            for (int j = 0; j < 8; ++j)
                uu[k][j] = Ub[nodes[k][j]];          // issue all 16 gathers now
#pragma unroll
            for (int j = 0; j < 8; ++j)
                atomicAdd(&sCnt[(unsigned)nodes[k][j] >> RSHIFT], 1u);
        }
    }
    __syncthreads();

    // pass B: one global tail reservation per (block, bucket)
    for (int b = threadIdx.x; b < n_buckets; b += K1_TPB) {
        unsigned c = sCnt[b];
        sBase[b] = c ? atomicAdd(&tails[b], c) : 0u;
        sCnt[b] = 0;                     // reuse as local cursor
    }
    __syncthreads();

    // pass C: unpack, matvec via ds_read_b128 filters, write 12 B records
#pragma unroll
    for (int k = 0; k < K1_EPT; ++k) {
        if (tt[k] < 0) continue;

        float ue[24];
#pragma unroll
        for (int j = 0; j < 8; ++j) {
            nuint2 v = uu[k][j];
            ue[3 * j + 0] = __uint_as_float(v.x << 16);
            ue[3 * j + 1] = __uint_as_float(v.x & 0xFFFF0000u);
            ue[3 * j + 2] = __uint_as_float(v.y << 16);
        }

        const float4* Kt4 = (const float4*)(sK + tt[k] * KSTRIDE);
#pragma unroll
        for (int j = 0; j < 8; ++j) {
            float a0 = 0.f, a1 = 0.f, a2 = 0.f;
#pragma unroll
            for (int q = 0; q < 6; ++q) {
                float4 k0 = Kt4[(3 * j + 0) * 6 + q];
                float4 k1 = Kt4[(3 * j + 1) * 6 + q];
                float4 k2 = Kt4[(3 * j + 2) * 6 + q];
                float u0 = ue[4 * q + 0], u1 = ue[4 * q + 1];
                float u2 = ue[4 * q + 2], u3 = ue[4 * q + 3];
                a0 += k0.x * u0 + k0.y * u1 + k0.z * u2 + k0.w * u3;
                a1 += k1.x * u0 + k1.y * u1 + k1.z * u2 + k1.w * u3;
                a2 += k2.x * u0 + k2.y * u1 + k2.z * u2 + k2.w * u3;
            }
            unsigned n = (unsigned)nodes[k][j];
            unsigned b = n >> RSHIFT;
            unsigned pos = sBase[b] + atomicAdd(&sCnt[b], 1u);
            if (pos < CAP) {
                unsigned local = n & (RNODES - 1);
                size_t base = 3 * ((size_t)b * CAP + pos);
                recs[base + 0] = (__float_as_uint(a0) & ~15u) | (local & 15u);
                recs[base + 1] = (__float_as_uint(a1) & ~15u) | ((local >> 4) & 15u);
                recs[base + 2] = (__float_as_uint(a2) & ~15u) | (local >> 8);
            } else {  // statistically unreachable; absolute correctness
                atomicAdd(&KU[(size_t)n * 3 + 0], a0);
                atomicAdd(&KU[(size_t)n * 3 + 1], a1);
                atomicAdd(&KU[(size_t)n * 3 + 2], a2);
            }
        }
    }
}

// ---- phase 2: accumulate per bucket --------------------------------------

__global__ __launch_bounds__(K2_TPB) void feconv_acc_kernel(
    const unsigned* __restrict__ recs,
    const unsigned* __restrict__ tails,
    float*          __restrict__ KU,     // [N, 3], pre-zeroed
    int n_nodes)
{
    __shared__ float sAcc[RNODES * 3];   // 24 KB
    const int b = blockIdx.x;

    for (int i = threadIdx.x; i < RNODES * 3; i += K2_TPB) sAcc[i] = 0.f;
    __syncthreads();

    unsigned cnt = tails[b];
    if (cnt > CAP) cnt = CAP;
    const unsigned* base = recs + 3 * ((size_t)b * CAP);
    for (unsigned i = threadIdx.x; i < cnt; i += K2_TPB) {
        unsigned w0 = base[3 * i + 0];
        unsigned w1 = base[3 * i + 1];
        unsigned w2 = base[3 * i + 2];
        unsigned local = (w0 & 15u) | ((w1 & 15u) << 4) | ((w2 & 7u) << 8);
        unsigned o = local * 3;
        atomicAdd(&sAcc[o + 0], __uint_as_float(w0 & ~15u));  // ds_add_f32
        atomicAdd(&sAcc[o + 1], __uint_as_float(w1 & ~15u));
        atomicAdd(&sAcc[o + 2], __uint_as_float(w2 & ~15u));
    }
    __syncthreads();

    const int nbase = b * RNODES;
    int limit = n_nodes - nbase;
    if (limit > RNODES) limit = RNODES;
    limit *= 3;
    float* out = KU + (size_t)nbase * 3;
    for (int i = threadIdx.x; i < limit; i += K2_TPB) out[i] += sAcc[i];
}

// ---- fallback (round-0 style) --------------------------------------------

__global__ __launch_bounds__(256) void feconv_elem_kernel(
    const float* __restrict__ U, const float* __restrict__ K,
    const int* __restrict__ types, const int* __restrict__ nodIdx,
    float* __restrict__ KU, int n_elems)
{
    int e = blockIdx.x * blockDim.x + threadIdx.x;
    if (e >= n_elems) return;
    int t = types[e];
    const int4* idx4 = (const int4*)(nodIdx + (size_t)e * 8);
    int4 iA = idx4[0], iB = idx4[1];
    int nodes[8] = {iA.x, iA.y, iA.z, iA.w, iB.x, iB.y, iB.z, iB.w};
    float ue[24];
#pragma unroll
    for (int j = 0; j < 8; ++j) {
        const float* up = U + (size_t)nodes[j] * 3;
        ue[3 * j + 0] = up[0]; ue[3 * j + 1] = up[1]; ue[3 * j + 2] = up[2];
    }
    const float* Kt = K + (size_t)t * 576;
#pragma unroll
    for (int i = 0; i < 24; ++i) {
        const float4* row = (const float4*)(Kt + i * 24);
        float acc = 0.f;
#pragma unroll
        for (int q = 0; q < 6; ++q) {
            float4 k = row[q];
            acc += k.x * ue[4 * q + 0] + k.y * ue[4 * q + 1]
                 + k.z * ue[4 * q + 2] + k.w * ue[4 * q + 3];
        }
        atomicAdd(&KU[(size_t)nodes[i / 3] * 3 + (i % 3)], acc);
    }
}

extern "C" void kernel_launch(void* const* d_in, const int* in_sizes, int n_in,
                              void* d_out, int out_size, void* d_ws, size_t ws_size,
                              hipStream_t stream) {
    const float* U      = (const float*)d_in[0];
    const float* Kf     = (const float*)d_in[1];
    const int*   types  = (const int*)d_in[2];
    const int*   nodIdx = (const int*)d_in[3];
    float*       KU     = (float*)d_out;

    const int n_elems = in_sizes[2];
    const int n_nodes = in_sizes[0] / 3;
    const int n_buckets = (n_nodes + RNODES - 1) / RNODES;   // 489 for N=1M

    (void)hipMemsetAsync(KU, 0, (size_t)out_size * sizeof(float), stream);

    // ws layout: [0, 4096) tails | [4096, +8B*n_nodes) Ub | then recs words
    const size_t ub_off  = 4096;
    const size_t rec_off = ub_off + (((size_t)n_nodes * 8 + 255) & ~255ull);
    const size_t need    = rec_off + (size_t)n_buckets * CAP * 12;

    if (n_buckets <= MAXB && ws_size >= need) {
        unsigned* tails = (unsigned*)d_ws;
        nuint2*   Ub    = (nuint2*)((char*)d_ws + ub_off);
        unsigned* recs  = (unsigned*)((char*)d_ws + rec_off);

        (void)hipMemsetAsync(tails, 0, 4096, stream);

        int gridP = (n_nodes + PREP_TPB - 1) / PREP_TPB;
        pack_u_kernel<<<gridP, PREP_TPB, 0, stream>>>(U, Ub, n_nodes);

        size_t lds_bytes = (size_t)NTYPES * KSTRIDE * sizeof(float);  // 148,480
        int grid1 = (n_elems + K1_CHUNK - 1) / K1_CHUNK;               // 245
        feconv_bin_kernel<<<grid1, K1_TPB, lds_bytes, stream>>>(
            Ub, Kf, types, nodIdx, KU, tails, recs, n_elems, n_buckets);
        feconv_acc_kernel<<<n_buckets, K2_TPB, 0, stream>>>(
            recs, tails, KU, n_nodes);
    } else {
        int block = 256;
        int grid = (n_elems + block - 1) / block;
        feconv_elem_kernel<<<grid, block, 0, stream>>>(
            U, Kf, types, nodIdx, KU, n_elems);
    }
}